// Round 7
// baseline (268.728 us; speedup 1.0000x reference)
//
#include <hip/hip_runtime.h>

// Capsule routing, factorized, all fp32, multi-kernel, plain stores only.
// Session ledger: R1 coop grid.sync ~60us each -> never. R2 contended global
// atomics -> never. R3 4 waves/CU = 294.8. R4 16 waves/CU = 289.4. R5 XCD
// swizzle + 640-thread squash = 264.7 (best). R6 = R5 + phase overlap but had
// a csm index bug (scale used n/10 storage-group instead of n/16 j-index) ->
// FAILED. R7 = R6 with the one-line fix: sc = csm[row*10 + (n>>4)].
// Overlap levers: (a) gemm1 hoists Xt loads above agg/softmax prologue (T14),
// (b) Ws padded to 12-float groups -> w reads 2xb128+1xb64 instead of 5xb64,
// (c) gemm2 hoists x prefetch above v-staging, (d) squash fully unrolled.
// B=256, K_IN=8, C=1152, J=10, D=16, 4 iters.
// m = k*1152 + c (M=9216), n = j*16 + d (N=160).

#define C_IN  1152
#define J_U   10
#define M_DIM 9216
#define N_DIM 160
#define B_SZ  256

// ---- ws layout (float offsets); ws is 256 MiB so offsets are generous ----
#define OFF_XT   0                    // [9216][256]
#define OFF_WR   2400000              // [9216][160]
#define OFF_SP   3900000              // [128][256][160]
#define OFF_V    9200000              // [256][160]
#define OFF_B0   9250000              // [1152][10]
#define OFF_B1   9270000              // [1152][10]
#define OFF_AG   9290000              // [32][1152][10]

// ================= prep: transpose x -> Xt, build Wr =================
__global__ __launch_bounds__(256) void k_prep(const float* __restrict__ x,
                                              const float* __restrict__ W,
                                              float* __restrict__ ws) {
    const int bid = blockIdx.x, t = threadIdx.x;
    if (bid < 576) {                       // 144 m-tiles x 4 b-tiles, 64x64 transpose
        __shared__ float T[64][65];
        const int m0 = (bid % 144) * 64, b0 = (bid / 144) * 64;
        {
            const int b_l = t >> 2, q = t & 3;
            const float* xp = x + (size_t)(b0 + b_l) * M_DIM + m0 + q * 16;
#pragma unroll
            for (int u = 0; u < 4; ++u) {
                const float4 v = *reinterpret_cast<const float4*>(xp + 4 * u);
                T[q * 16 + 4 * u + 0][b_l] = v.x;
                T[q * 16 + 4 * u + 1][b_l] = v.y;
                T[q * 16 + 4 * u + 2][b_l] = v.z;
                T[q * 16 + 4 * u + 3][b_l] = v.w;
            }
        }
        __syncthreads();
        {
            const int m_l = t >> 2, q = t & 3;
            float* Xt = ws + OFF_XT;
            float4* op = reinterpret_cast<float4*>(Xt + (size_t)(m0 + m_l) * B_SZ + b0 + q * 16);
#pragma unroll
            for (int u = 0; u < 4; ++u)
                op[u] = make_float4(T[m_l][q * 16 + 4 * u], T[m_l][q * 16 + 4 * u + 1],
                                    T[m_l][q * 16 + 4 * u + 2], T[m_l][q * 16 + 4 * u + 3]);
        }
    } else {                               // Wr[(k*C+c)][n] = W[c][n][k]
        const int i = (bid - 576) * 256 + t;    // [0, 368640)
        const int n = i % N_DIM;
        const int c = (i / N_DIM) % C_IN;
        const int kh = i / (N_DIM * C_IN);      // 0..1
        const float4 w = *reinterpret_cast<const float4*>(W + (size_t)c * 1280 + n * 8 + kh * 4);
        float* Wr = ws + OFF_WR;
        const float wv[4] = {w.x, w.y, w.z, w.w};
#pragma unroll
        for (int j = 0; j < 4; ++j)
            Wr[(size_t)((kh * 4 + j) * C_IN + c) * N_DIM + n] = wv[j];
    }
}

// ================= gemm1: 128 chunks(72 m) x 4 b-quarters(64 b) = 512 blocks =======
// XCD swizzle (R5). Hoisted Xt loads overlap the agg/softmax prologue (vmcnt
// ordering: agg loads issued after, so waiting for them covers Xt too).
// Ws stored [72][16 grp][12] (10 used + 2 pad) -> main-loop w reads are
// 2xb128+1xb64 broadcast (3 issues vs 5). LDS 79488 B -> still 2 blocks/CU.
__global__ __launch_bounds__(256, 2) void k_gemm1(const float* __restrict__ Xt,
                                                  const float2* __restrict__ Wr2,
                                                  const float* __restrict__ bij_old,
                                                  float* __restrict__ bij_new,
                                                  const float* __restrict__ agg_part,
                                                  float* __restrict__ s_part,
                                                  int first) {
    __shared__ float braw[720];
    __shared__ float csm[720];
    __shared__ float Ws[72 * 192];                  // padded n-groups
    __shared__ alignas(16) float Xs[72 * 64];
    const int vb = (blockIdx.x & 7) * 64 + (blockIdx.x >> 3);   // XCD-aware remap
    const int ch = vb >> 2, bq4 = vb & 3;
    const int m0 = ch * 72;
    const int c0 = (ch & 15) * 72;        // chunk sits inside one k-slice (1152/72=16)
    const int t = threadIdx.x;

    // ---- hoisted Xt loads: 72 rows x 16 float4; thread covers col (t&15), rows t>>4 + 16k
    const int xr = t >> 4, xc = (t & 15) * 4;
    const float* Xb = Xt + (size_t)m0 * B_SZ + bq4 * 64 + xc;
    const float4 hx0 = *reinterpret_cast<const float4*>(Xb + (size_t)(xr     ) * B_SZ);
    const float4 hx1 = *reinterpret_cast<const float4*>(Xb + (size_t)(xr + 16) * B_SZ);
    const float4 hx2 = *reinterpret_cast<const float4*>(Xb + (size_t)(xr + 32) * B_SZ);
    const float4 hx3 = *reinterpret_cast<const float4*>(Xb + (size_t)(xr + 48) * B_SZ);
    float4 hx4 = make_float4(0.f, 0.f, 0.f, 0.f);
    if (xr < 8) hx4 = *reinterpret_cast<const float4*>(Xb + (size_t)(xr + 64) * B_SZ);

    if (first) {
        // b_ij == 0: softmax(0) = 1/J exactly; skip the 32-slice agg read.
        for (int idx = t; idx < 720; idx += 256) {
            csm[idx] = 0.1f;
            bij_new[c0 * J_U + idx] = 0.f;
        }
    } else {
        for (int idx = t; idx < 720; idx += 256) {
            float v = bij_old[c0 * J_U + idx];
#pragma unroll
            for (int s = 0; s < 32; ++s) v += agg_part[s * 11520 + c0 * J_U + idx];
            braw[idx] = v;
            bij_new[c0 * J_U + idx] = v;   // bq-duplicate writes are identical values
        }
    }
    // ---- write hoisted x panel to LDS (loads have drained behind agg reads) ----
    *reinterpret_cast<float4*>(&Xs[(xr     ) * 64 + xc]) = hx0;
    *reinterpret_cast<float4*>(&Xs[(xr + 16) * 64 + xc]) = hx1;
    *reinterpret_cast<float4*>(&Xs[(xr + 32) * 64 + xc]) = hx2;
    *reinterpret_cast<float4*>(&Xs[(xr + 48) * 64 + xc]) = hx3;
    if (xr < 8) *reinterpret_cast<float4*>(&Xs[(xr + 64) * 64 + xc]) = hx4;
    __syncthreads();
    if (!first) {
        for (int idx = t; idx < 720; idx += 256) {    // softmax over j
            const int r0 = (idx / J_U) * J_U;
            float mx = -1e30f;
#pragma unroll
            for (int j = 0; j < J_U; ++j) mx = fmaxf(mx, braw[r0 + j]);
            float sum = 0.f;
#pragma unroll
            for (int j = 0; j < J_U; ++j) sum += __expf(braw[r0 + j] - mx);
            csm[idx] = __expf(braw[idx] - mx) / sum;
        }
        __syncthreads();
    }
    // ---- stage scaled W panel: float2 pairs; scale index is j = n>>4 (R6 bug: used n/10) ----
    for (int i = t; i < 5760; i += 256) {          // 72 rows x 80 float2
        const int row = i / 80, p = i - row * 80;
        const int n = 2 * p, g = n / J_U, o = n - g * J_U;   // storage group g, offset o
        const float sc = csm[row * J_U + (n >> 4)];          // softmax j-index = n/16
        const float2 w = Wr2[(size_t)(m0 + row) * 80 + p];
        *reinterpret_cast<float2*>(&Ws[row * 192 + g * 12 + o]) =
            make_float2(w.x * sc, w.y * sc);
    }
    __syncthreads();
    // ---- main loop: x b128 (2-way free) + w 2xb128+1xb64 broadcast per 40 FMA ----
    const int bq = t & 15, ng = t >> 4;
    float acc[4][10] = {};
#pragma unroll 4
    for (int m = 0; m < 72; ++m) {
        const float4 cur = *reinterpret_cast<const float4*>(&Xs[m * 64 + bq * 4]);
        const float* wr = Ws + m * 192 + ng * 12;
        const float4 wa = *reinterpret_cast<const float4*>(wr);
        const float4 wb = *reinterpret_cast<const float4*>(wr + 4);
        const float2 wc = *reinterpret_cast<const float2*>(wr + 8);
        const float xv[4] = {cur.x, cur.y, cur.z, cur.w};
        const float wv[10] = {wa.x, wa.y, wa.z, wa.w, wb.x, wb.y, wb.z, wb.w, wc.x, wc.y};
#pragma unroll
        for (int q = 0; q < 10; ++q)
#pragma unroll
            for (int i = 0; i < 4; ++i)
                acc[i][q] += xv[i] * wv[q];
    }
    // ---- store split-K partials (plain stores, layout identical) ----
    float* sp = s_part + (size_t)ch * 40960 + (size_t)(bq4 * 64 + bq * 4) * N_DIM + ng * J_U;
#pragma unroll
    for (int i = 0; i < 4; ++i) {
        float2* p = reinterpret_cast<float2*>(sp + (size_t)i * N_DIM);
#pragma unroll
        for (int jj = 0; jj < 5; ++jj) p[jj] = make_float2(acc[i][2 * jj], acc[i][2 * jj + 1]);
    }
}

// ================= squash: reduce 128 slices (4-way h-split), squash -> dst ========
__global__ __launch_bounds__(640) void k_squash(const float* __restrict__ s_part,
                                                float* __restrict__ dst) {
    __shared__ float red[640];
    __shared__ float sq[160];
    const int b = blockIdx.x, t = threadIdx.x;
    const int n = t % 160, h = t / 160;            // h in 0..3, 32 slices each
    float s = 0.f;
    const float* p = s_part + (size_t)h * 32 * 40960 + (size_t)b * N_DIM + n;
#pragma unroll                                      // full unroll: 32 loads in flight
    for (int sl = 0; sl < 32; ++sl) s += p[(size_t)sl * 40960];
    red[t] = s;
    __syncthreads();
    if (t < 160) {
        s = red[t] + red[t + 160] + red[t + 320] + red[t + 480] + 1e-5f;  // +1e-5 BEFORE mags
        sq[t] = s * s;
        red[t] = s;
    }
    __syncthreads();
    if (t < 160) {
        const int j0 = t & ~15;
        float mag = 0.f;
#pragma unroll
        for (int d = 0; d < 16; ++d) mag += sq[j0 + d];
        dst[(size_t)b * N_DIM + t] = red[t] * (sqrtf(mag) / (1.f + mag));
    }
}

// ================= gemm2: 144 m-tiles(64) x 4 b-quarters(64 b) = 576 blocks =========
// XCD swizzle (R5). x prefetch hoisted above v-staging so HBM/L2 latency of the
// first 4 rows hides under the 41KB v-panel stage.
__global__ __launch_bounds__(256) void k_gemm2(const float* __restrict__ x,
                                               const float* __restrict__ v,
                                               const float* __restrict__ Wr,
                                               float* __restrict__ agg_part) {
    __shared__ alignas(16) float VG[64 * 164];   // v-panel [64][160] then G-tile [64][164]
    __shared__ float agg[640];                   // 64 c x 10 j
    const int vb = (blockIdx.x % 8) * 72 + (blockIdx.x / 8);    // XCD-aware remap
    const int mt = vb >> 2, bq = vb & 3;
    const int m0 = mt * 64, b0 = bq * 64;
    const int t = threadIdx.x;
    const int tm = t & 15, ng = t >> 4;

    // hoisted x prefetch (global-only, independent of LDS state)
    const float* xb = x + (size_t)b0 * M_DIM + m0 + tm * 4;
    float4 pf[4];
#pragma unroll
    for (int i = 0; i < 4; ++i) pf[i] = *reinterpret_cast<const float4*>(xb + (size_t)i * M_DIM);

    // stage v quarter (packed [64][160])
    float4* Vs4 = reinterpret_cast<float4*>(VG);
    const float4* v4 = reinterpret_cast<const float4*>(v);
    for (int i = t; i < 2560; i += 256) Vs4[i] = v4[(size_t)bq * 2560 + i];
    for (int i = t; i < 640; i += 256) agg[i] = 0.f;
    __syncthreads();

    // main loop over 64 b: x coalesced (256B/wave-instr), v broadcast from LDS
    float acc[4][10] = {};
    const float2* Vs2 = reinterpret_cast<const float2*>(VG);
#pragma unroll 4
    for (int b = 0; b < 64; ++b) {
        const int bf = (b + 4 < 64) ? b + 4 : 63;            // clamped prefetch
        const float4 nxt = *reinterpret_cast<const float4*>(xb + (size_t)bf * M_DIM);
        const float4 cur = pf[0];
        pf[0] = pf[1]; pf[1] = pf[2]; pf[2] = pf[3]; pf[3] = nxt;
        const float2* vv = Vs2 + b * 80 + ng * 5;
        const float xv[4] = {cur.x, cur.y, cur.z, cur.w};
#pragma unroll
        for (int jj = 0; jj < 5; ++jj) {
            const float2 w = vv[jj];
#pragma unroll
            for (int i = 0; i < 4; ++i) {
                acc[i][2 * jj]     += xv[i] * w.x;
                acc[i][2 * jj + 1] += xv[i] * w.y;
            }
        }
    }
    __syncthreads();   // all waves done reading v-panel; reuse VG for G-tile
    // scatter acc -> G-tile (row stride 164 floats = 656 B, 16B-aligned rows)
#pragma unroll
    for (int i = 0; i < 4; ++i)
#pragma unroll
        for (int q = 0; q < 10; ++q)
            VG[(tm * 4 + i) * 164 + ng * 10 + q] = acc[i][q];
    __syncthreads();
    // coalesced fold: 64 rows x 40 float4 of Wr ⊙ G, one j per float4
    const float4* Wr4 = reinterpret_cast<const float4*>(Wr);
    for (int idx = t; idx < 2560; idx += 256) {
        const int row = idx / 40, q = idx - row * 40;
        const float4 w = Wr4[(size_t)(m0 + row) * 40 + q];
        const float4 g = *reinterpret_cast<const float4*>(&VG[row * 164 + q * 4]);
        atomicAdd(&agg[row * J_U + (q >> 2)], w.x * g.x + w.y * g.y + w.z * g.z + w.w * g.w);
    }
    __syncthreads();
    const int k = m0 / C_IN, c0 = m0 - k * C_IN;   // 64-tile never crosses a k-slice
    for (int i = t; i < 640; i += 256)
        agg_part[(size_t)(bq * 8 + k) * 11520 + c0 * J_U + i] = agg[i];
}

extern "C" void kernel_launch(void* const* d_in, const int* in_sizes, int n_in,
                              void* d_out, int out_size, void* d_ws, size_t ws_size,
                              hipStream_t stream) {
    const float* x = (const float*)d_in[0];   // (256, 8, 1152) fp32
    const float* W = (const float*)d_in[1];   // (1, 1152, 10, 16, 8) fp32
    float* out = (float*)d_out;               // (256, 10, 16, 1) fp32
    float* ws  = (float*)d_ws;
    float* Xt   = ws + OFF_XT;
    float* Wr   = ws + OFF_WR;
    float* sp   = ws + OFF_SP;
    float* v    = ws + OFF_V;
    float* bij0 = ws + OFF_B0;
    float* bij1 = ws + OFF_B1;
    float* agg  = ws + OFF_AG;
    const float2* Wr2 = (const float2*)Wr;

    k_prep<<<2016, 256, 0, stream>>>(x, W, ws);

    for (int it = 0; it < 4; ++it) {
        const float* bo = (it & 1) ? bij1 : bij0;
        float*       bn = (it & 1) ? bij0 : bij1;
        k_gemm1<<<512, 256, 0, stream>>>(Xt, Wr2, bo, bn, agg, sp, it == 0 ? 1 : 0);
        k_squash<<<256, 640, 0, stream>>>(sp, (it < 3) ? v : out);
        if (it < 3)   // last iteration's agreement is never used
            k_gemm2<<<576, 256, 0, stream>>>(x, v, Wr, agg);
    }
}

// Round 8
// 254.657 us; speedup vs baseline: 1.0553x; 1.0553x over previous
//
#include <hip/hip_runtime.h>
#include <hip/hip_fp16.h>

// Capsule routing, factorized, multi-kernel, plain stores only.
// Session ledger: R1 coop grid.sync ~60us each -> never. R2 contended global
// atomics -> never. R3 4 waves/CU = 294.8. R4 16 waves/CU = 289.4.
// R5 XCD swizzle + 640-thread squash = 264.7 (best). R7 phase-overlap bundle
// (hoisted loads, padded Ws, unrolled squash) = 268.7 -> reverted.
// R8 = R5 + s_part stored as fp16x2 (halves the 42 MB/iter split-K round trip;
// fp16 not bf16: partials ~+-50 << 65504, rel err 2^-11 -> v err ~2e-4, 17x
// under threshold; bf16's 2^-8 would risk softmax feedback amplification).
// B=256, K_IN=8, C=1152, J=10, D=16, 4 iters.
// m = k*1152 + c (M=9216), n = j*16 + d (N=160).

#define C_IN  1152
#define J_U   10
#define M_DIM 9216
#define N_DIM 160
#define B_SZ  256

// ---- ws layout (float offsets); ws is 256 MiB so offsets are generous ----
#define OFF_XT   0                    // [9216][256] fp32
#define OFF_WR   2400000              // [9216][160] fp32
#define OFF_SP   3900000              // [128][256][80] half2 (10.5 MB)
#define OFF_V    9200000              // [256][160] fp32
#define OFF_B0   9250000              // [1152][10]
#define OFF_B1   9270000              // [1152][10]
#define OFF_AG   9290000              // [32][1152][10]

// ================= prep: transpose x -> Xt, build Wr (R5, proven) =================
__global__ __launch_bounds__(256) void k_prep(const float* __restrict__ x,
                                              const float* __restrict__ W,
                                              float* __restrict__ ws) {
    const int bid = blockIdx.x, t = threadIdx.x;
    if (bid < 576) {                       // 144 m-tiles x 4 b-tiles, 64x64 transpose
        __shared__ float T[64][65];
        const int m0 = (bid % 144) * 64, b0 = (bid / 144) * 64;
        {
            const int b_l = t >> 2, q = t & 3;
            const float* xp = x + (size_t)(b0 + b_l) * M_DIM + m0 + q * 16;
#pragma unroll
            for (int u = 0; u < 4; ++u) {
                const float4 v = *reinterpret_cast<const float4*>(xp + 4 * u);
                T[q * 16 + 4 * u + 0][b_l] = v.x;
                T[q * 16 + 4 * u + 1][b_l] = v.y;
                T[q * 16 + 4 * u + 2][b_l] = v.z;
                T[q * 16 + 4 * u + 3][b_l] = v.w;
            }
        }
        __syncthreads();
        {
            const int m_l = t >> 2, q = t & 3;
            float* Xt = ws + OFF_XT;
            float4* op = reinterpret_cast<float4*>(Xt + (size_t)(m0 + m_l) * B_SZ + b0 + q * 16);
#pragma unroll
            for (int u = 0; u < 4; ++u)
                op[u] = make_float4(T[m_l][q * 16 + 4 * u], T[m_l][q * 16 + 4 * u + 1],
                                    T[m_l][q * 16 + 4 * u + 2], T[m_l][q * 16 + 4 * u + 3]);
        }
    } else {                               // Wr[(k*C+c)][n] = W[c][n][k]
        const int i = (bid - 576) * 256 + t;    // [0, 368640)
        const int n = i % N_DIM;
        const int c = (i / N_DIM) % C_IN;
        const int kh = i / (N_DIM * C_IN);      // 0..1
        const float4 w = *reinterpret_cast<const float4*>(W + (size_t)c * 1280 + n * 8 + kh * 4);
        float* Wr = ws + OFF_WR;
        const float wv[4] = {w.x, w.y, w.z, w.w};
#pragma unroll
        for (int j = 0; j < 4; ++j)
            Wr[(size_t)((kh * 4 + j) * C_IN + c) * N_DIM + n] = wv[j];
    }
}

// ================= gemm1: 128 chunks(72 m) x 4 b-quarters(64 b) = 512 blocks =======
// R5 body; epilogue packs acc pairs to fp16x2 (halves split-K write traffic).
__global__ __launch_bounds__(256, 2) void k_gemm1(const float* __restrict__ Xt,
                                                  const float4* __restrict__ Wr4,
                                                  const float* __restrict__ bij_old,
                                                  float* __restrict__ bij_new,
                                                  const float* __restrict__ agg_part,
                                                  __half2* __restrict__ s_part,
                                                  int first) {
    __shared__ float braw[720];
    __shared__ float csm[720];
    __shared__ float Ws[72 * 160];
    __shared__ alignas(16) float Xs[72 * 64];
    const int vb = (blockIdx.x & 7) * 64 + (blockIdx.x >> 3);   // XCD-aware remap
    const int ch = vb >> 2, bq4 = vb & 3;
    const int m0 = ch * 72;
    const int c0 = (ch & 15) * 72;        // chunk sits inside one k-slice (1152/72=16)
    const int t = threadIdx.x;

    if (first) {
        // b_ij == 0: softmax(0) = 1/J exactly; skip the 32-slice agg read.
        for (int idx = t; idx < 720; idx += 256) {
            csm[idx] = 0.1f;
            bij_new[c0 * J_U + idx] = 0.f;
        }
    } else {
        for (int idx = t; idx < 720; idx += 256) {
            float v = bij_old[c0 * J_U + idx];
#pragma unroll
            for (int s = 0; s < 32; ++s) v += agg_part[s * 11520 + c0 * J_U + idx];
            braw[idx] = v;
            bij_new[c0 * J_U + idx] = v;   // bq-duplicate writes are identical values
        }
        __syncthreads();
        for (int idx = t; idx < 720; idx += 256) {    // softmax over j
            const int r0 = (idx / J_U) * J_U;
            float mx = -1e30f;
#pragma unroll
            for (int j = 0; j < J_U; ++j) mx = fmaxf(mx, braw[r0 + j]);
            float sum = 0.f;
#pragma unroll
            for (int j = 0; j < J_U; ++j) sum += __expf(braw[r0 + j] - mx);
            csm[idx] = __expf(braw[idx] - mx) / sum;
        }
    }
    __syncthreads();
    // ---- stage scaled W panel + x panel ----
    float4* Ws4 = reinterpret_cast<float4*>(Ws);
    for (int i = t; i < 2880; i += 256) {          // 72 rows x 40 float4
        const int row = i / 40, q = i - row * 40;
        const float sc = csm[row * J_U + (q >> 2)];
        const float4 w = Wr4[(size_t)(m0 + row) * 40 + q];
        Ws4[i] = make_float4(w.x * sc, w.y * sc, w.z * sc, w.w * sc);
    }
    for (int i = t; i < 1152; i += 256) {          // 72 rows x 16 float4 (64 b each)
        const int row = i >> 4, col = i & 15;
        const float4 xv = *reinterpret_cast<const float4*>(
            Xt + (size_t)(m0 + row) * B_SZ + bq4 * 64 + col * 4);
        *reinterpret_cast<float4*>(&Xs[row * 64 + col * 4]) = xv;
    }
    __syncthreads();
    // ---- main loop: pure LDS (x b128 conflict-free, w b64 broadcast) ----
    const int bq = t & 15, ng = t >> 4;
    float acc[4][10] = {};
#pragma unroll 4
    for (int m = 0; m < 72; ++m) {
        const float4 cur = *reinterpret_cast<const float4*>(&Xs[m * 64 + bq * 4]);
        const float2* wr = reinterpret_cast<const float2*>(Ws + m * N_DIM + ng * J_U);
        const float xv[4] = {cur.x, cur.y, cur.z, cur.w};
#pragma unroll
        for (int jj = 0; jj < 5; ++jj) {
            const float2 wv = wr[jj];
#pragma unroll
            for (int i = 0; i < 4; ++i) {
                acc[i][2 * jj]     += xv[i] * wv.x;
                acc[i][2 * jj + 1] += xv[i] * wv.y;
            }
        }
    }
    // ---- store split-K partials as fp16x2 (plain stores, half the bytes) ----
    __half2* sp = s_part + (size_t)ch * 20480 + (size_t)(bq4 * 64 + bq * 4) * 80 + ng * 5;
#pragma unroll
    for (int i = 0; i < 4; ++i)
#pragma unroll
        for (int jj = 0; jj < 5; ++jj)
            sp[(size_t)i * 80 + jj] = __floats2half2_rn(acc[i][2 * jj], acc[i][2 * jj + 1]);
}

// ================= squash: reduce 128 fp16x2 slices (8-way h-split) -> dst ========
// 640 threads = 80 n-pairs x 8 h-groups (16 slices each, fully unrolled).
// fp32 accumulation; +1e-5 added once after the full 128-slice sum (ref order).
__global__ __launch_bounds__(640) void k_squash(const __half2* __restrict__ s_part,
                                                float* __restrict__ dst) {
    __shared__ float2 red[640];                    // [h][80]
    __shared__ float sq[160];
    const int b = blockIdx.x, t = threadIdx.x;
    const int n2 = t % 80, h = t / 80;             // h in 0..7, 16 slices each
    float2 acc = make_float2(0.f, 0.f);
    const __half2* p = s_part + (size_t)h * 16 * 20480 + (size_t)b * 80 + n2;
#pragma unroll
    for (int sl = 0; sl < 16; ++sl) {
        const float2 f = __half22float2(p[(size_t)sl * 20480]);
        acc.x += f.x;
        acc.y += f.y;
    }
    red[t] = acc;
    __syncthreads();
    if (t < 80) {
        float2 s = red[t];
#pragma unroll
        for (int hh = 1; hh < 8; ++hh) {
            const float2 r = red[t + hh * 80];
            s.x += r.x;
            s.y += r.y;
        }
        s.x += 1e-5f;                              // +1e-5 BEFORE magnitudes (ref)
        s.y += 1e-5f;
        sq[2 * t]     = s.x * s.x;
        sq[2 * t + 1] = s.y * s.y;
        red[t] = s;
    }
    __syncthreads();
    if (t < 80) {
        // n = 2t, 2t+1 share j = n>>4 (2t even)
        const int j0 = (t >> 3) * 16;
        float mag = 0.f;
#pragma unroll
        for (int d = 0; d < 16; ++d) mag += sq[j0 + d];
        const float sc = sqrtf(mag) / (1.f + mag);
        const float2 s = red[t];
        dst[(size_t)b * N_DIM + 2 * t]     = s.x * sc;
        dst[(size_t)b * N_DIM + 2 * t + 1] = s.y * sc;
    }
}

// ================= gemm2: 144 m-tiles(64) x 4 b-quarters(64 b) = 576 blocks =========
// R5 version, byte-identical (XCD swizzle).
__global__ __launch_bounds__(256) void k_gemm2(const float* __restrict__ x,
                                               const float* __restrict__ v,
                                               const float* __restrict__ Wr,
                                               float* __restrict__ agg_part) {
    __shared__ alignas(16) float VG[64 * 164];   // v-panel [64][160] then G-tile [64][164]
    __shared__ float agg[640];                   // 64 c x 10 j
    const int vb = (blockIdx.x % 8) * 72 + (blockIdx.x / 8);    // XCD-aware remap
    const int mt = vb >> 2, bq = vb & 3;
    const int m0 = mt * 64, b0 = bq * 64;
    const int t = threadIdx.x;
    const int tm = t & 15, ng = t >> 4;

    // stage v quarter (packed [64][160])
    float4* Vs4 = reinterpret_cast<float4*>(VG);
    const float4* v4 = reinterpret_cast<const float4*>(v);
    for (int i = t; i < 2560; i += 256) Vs4[i] = v4[(size_t)bq * 2560 + i];
    for (int i = t; i < 640; i += 256) agg[i] = 0.f;
    __syncthreads();

    // main loop over 64 b: x coalesced (256B/wave-instr), v broadcast from LDS
    float acc[4][10] = {};
    const float* xb = x + (size_t)b0 * M_DIM + m0 + tm * 4;
    const float2* Vs2 = reinterpret_cast<const float2*>(VG);
    float4 pf[4];
#pragma unroll
    for (int i = 0; i < 4; ++i) pf[i] = *reinterpret_cast<const float4*>(xb + (size_t)i * M_DIM);
#pragma unroll 4
    for (int b = 0; b < 64; ++b) {
        const int bf = (b + 4 < 64) ? b + 4 : 63;            // clamped prefetch
        const float4 nxt = *reinterpret_cast<const float4*>(xb + (size_t)bf * M_DIM);
        const float4 cur = pf[0];
        pf[0] = pf[1]; pf[1] = pf[2]; pf[2] = pf[3]; pf[3] = nxt;
        const float2* vv = Vs2 + b * 80 + ng * 5;
        const float xv[4] = {cur.x, cur.y, cur.z, cur.w};
#pragma unroll
        for (int jj = 0; jj < 5; ++jj) {
            const float2 w = vv[jj];
#pragma unroll
            for (int i = 0; i < 4; ++i) {
                acc[i][2 * jj]     += xv[i] * w.x;
                acc[i][2 * jj + 1] += xv[i] * w.y;
            }
        }
    }
    __syncthreads();   // all waves done reading v-panel; reuse VG for G-tile
    // scatter acc -> G-tile (row stride 164 floats = 656 B, 16B-aligned rows)
#pragma unroll
    for (int i = 0; i < 4; ++i)
#pragma unroll
        for (int q = 0; q < 10; ++q)
            VG[(tm * 4 + i) * 164 + ng * 10 + q] = acc[i][q];
    __syncthreads();
    // coalesced fold: 64 rows x 40 float4 of Wr ⊙ G, one j per float4
    const float4* Wr4 = reinterpret_cast<const float4*>(Wr);
    for (int idx = t; idx < 2560; idx += 256) {
        const int row = idx / 40, q = idx - row * 40;
        const float4 w = Wr4[(size_t)(m0 + row) * 40 + q];
        const float4 g = *reinterpret_cast<const float4*>(&VG[row * 164 + q * 4]);
        atomicAdd(&agg[row * J_U + (q >> 2)], w.x * g.x + w.y * g.y + w.z * g.z + w.w * g.w);
    }
    __syncthreads();
    const int k = m0 / C_IN, c0 = m0 - k * C_IN;   // 64-tile never crosses a k-slice
    for (int i = t; i < 640; i += 256)
        agg_part[(size_t)(bq * 8 + k) * 11520 + c0 * J_U + i] = agg[i];
}

extern "C" void kernel_launch(void* const* d_in, const int* in_sizes, int n_in,
                              void* d_out, int out_size, void* d_ws, size_t ws_size,
                              hipStream_t stream) {
    const float* x = (const float*)d_in[0];   // (256, 8, 1152) fp32
    const float* W = (const float*)d_in[1];   // (1, 1152, 10, 16, 8) fp32
    float* out = (float*)d_out;               // (256, 10, 16, 1) fp32
    float* ws  = (float*)d_ws;
    float* Xt   = ws + OFF_XT;
    float* Wr   = ws + OFF_WR;
    __half2* sp = (__half2*)(ws + OFF_SP);
    float* v    = ws + OFF_V;
    float* bij0 = ws + OFF_B0;
    float* bij1 = ws + OFF_B1;
    float* agg  = ws + OFF_AG;
    const float4* Wr4 = (const float4*)Wr;

    k_prep<<<2016, 256, 0, stream>>>(x, W, ws);

    for (int it = 0; it < 4; ++it) {
        const float* bo = (it & 1) ? bij1 : bij0;
        float*       bn = (it & 1) ? bij0 : bij1;
        k_gemm1<<<512, 256, 0, stream>>>(Xt, Wr4, bo, bn, agg, sp, it == 0 ? 1 : 0);
        k_squash<<<256, 640, 0, stream>>>(sp, (it < 3) ? v : out);
        if (it < 3)   // last iteration's agreement is never used
            k_gemm2<<<576, 256, 0, stream>>>(x, v, Wr, agg);
    }
}

// Round 9
// 248.790 us; speedup vs baseline: 1.0801x; 1.0236x over previous
//
#include <hip/hip_runtime.h>
#include <hip/hip_fp16.h>

// Capsule routing, factorized, multi-kernel, plain stores only.
// Session ledger: R1 coop grid.sync ~60us -> never. R2 contended atomics ->
// never. R3 4 waves/CU = 294.8. R4 16 waves/CU = 289.4. R5 XCD swizzle = 264.7.
// R7 phase-overlap bundle = 268.7 -> reverted. R8 fp16 split-K = 254.7 (best).
// R9 = R8 + packed fp32 math: inner loops rewritten on float2 vectors so hipcc
// contracts to v_pk_fma_f32 (VOP3P, 2x fp32 FMA/instr). FMA floor per GEMM iter
// is 19.2us scalar (377M FMA / 256 CU / 64 lanes x 2cyc); packing halves it.
// Accumulators pair along n so the LDS float2 w/v reads feed the pair directly;
// x side is a 2-lane splat hoisted per m-step (4 movs vs 20 instrs saved).
// B=256, K_IN=8, C=1152, J=10, D=16, 4 iters.
// m = k*1152 + c (M=9216), n = j*16 + d (N=160).

typedef float v2f __attribute__((ext_vector_type(2)));

#define C_IN  1152
#define J_U   10
#define M_DIM 9216
#define N_DIM 160
#define B_SZ  256

// ---- ws layout (float offsets); ws is 256 MiB so offsets are generous ----
#define OFF_XT   0                    // [9216][256] fp32
#define OFF_WR   2400000              // [9216][160] fp32
#define OFF_SP   3900000              // [128][256][80] half2 (10.5 MB)
#define OFF_V    9200000              // [256][160] fp32
#define OFF_B0   9250000              // [1152][10]
#define OFF_B1   9270000              // [1152][10]
#define OFF_AG   9290000              // [32][1152][10]

// ================= prep: transpose x -> Xt, build Wr (R5, proven) =================
__global__ __launch_bounds__(256) void k_prep(const float* __restrict__ x,
                                              const float* __restrict__ W,
                                              float* __restrict__ ws) {
    const int bid = blockIdx.x, t = threadIdx.x;
    if (bid < 576) {                       // 144 m-tiles x 4 b-tiles, 64x64 transpose
        __shared__ float T[64][65];
        const int m0 = (bid % 144) * 64, b0 = (bid / 144) * 64;
        {
            const int b_l = t >> 2, q = t & 3;
            const float* xp = x + (size_t)(b0 + b_l) * M_DIM + m0 + q * 16;
#pragma unroll
            for (int u = 0; u < 4; ++u) {
                const float4 v = *reinterpret_cast<const float4*>(xp + 4 * u);
                T[q * 16 + 4 * u + 0][b_l] = v.x;
                T[q * 16 + 4 * u + 1][b_l] = v.y;
                T[q * 16 + 4 * u + 2][b_l] = v.z;
                T[q * 16 + 4 * u + 3][b_l] = v.w;
            }
        }
        __syncthreads();
        {
            const int m_l = t >> 2, q = t & 3;
            float* Xt = ws + OFF_XT;
            float4* op = reinterpret_cast<float4*>(Xt + (size_t)(m0 + m_l) * B_SZ + b0 + q * 16);
#pragma unroll
            for (int u = 0; u < 4; ++u)
                op[u] = make_float4(T[m_l][q * 16 + 4 * u], T[m_l][q * 16 + 4 * u + 1],
                                    T[m_l][q * 16 + 4 * u + 2], T[m_l][q * 16 + 4 * u + 3]);
        }
    } else {                               // Wr[(k*C+c)][n] = W[c][n][k]
        const int i = (bid - 576) * 256 + t;    // [0, 368640)
        const int n = i % N_DIM;
        const int c = (i / N_DIM) % C_IN;
        const int kh = i / (N_DIM * C_IN);      // 0..1
        const float4 w = *reinterpret_cast<const float4*>(W + (size_t)c * 1280 + n * 8 + kh * 4);
        float* Wr = ws + OFF_WR;
        const float wv[4] = {w.x, w.y, w.z, w.w};
#pragma unroll
        for (int j = 0; j < 4; ++j)
            Wr[(size_t)((kh * 4 + j) * C_IN + c) * N_DIM + n] = wv[j];
    }
}

// ================= gemm1: 128 chunks(72 m) x 4 b-quarters(64 b) = 512 blocks =======
// R8 body; inner loop on float2 pairs (n-dim) -> v_pk_fma_f32.
__global__ __launch_bounds__(256, 2) void k_gemm1(const float* __restrict__ Xt,
                                                  const float4* __restrict__ Wr4,
                                                  const float* __restrict__ bij_old,
                                                  float* __restrict__ bij_new,
                                                  const float* __restrict__ agg_part,
                                                  __half2* __restrict__ s_part,
                                                  int first) {
    __shared__ float braw[720];
    __shared__ float csm[720];
    __shared__ float Ws[72 * 160];
    __shared__ alignas(16) float Xs[72 * 64];
    const int vb = (blockIdx.x & 7) * 64 + (blockIdx.x >> 3);   // XCD-aware remap
    const int ch = vb >> 2, bq4 = vb & 3;
    const int m0 = ch * 72;
    const int c0 = (ch & 15) * 72;        // chunk sits inside one k-slice (1152/72=16)
    const int t = threadIdx.x;

    if (first) {
        // b_ij == 0: softmax(0) = 1/J exactly; skip the 32-slice agg read.
        for (int idx = t; idx < 720; idx += 256) {
            csm[idx] = 0.1f;
            bij_new[c0 * J_U + idx] = 0.f;
        }
    } else {
        for (int idx = t; idx < 720; idx += 256) {
            float v = bij_old[c0 * J_U + idx];
#pragma unroll
            for (int s = 0; s < 32; ++s) v += agg_part[s * 11520 + c0 * J_U + idx];
            braw[idx] = v;
            bij_new[c0 * J_U + idx] = v;   // bq-duplicate writes are identical values
        }
        __syncthreads();
        for (int idx = t; idx < 720; idx += 256) {    // softmax over j
            const int r0 = (idx / J_U) * J_U;
            float mx = -1e30f;
#pragma unroll
            for (int j = 0; j < J_U; ++j) mx = fmaxf(mx, braw[r0 + j]);
            float sum = 0.f;
#pragma unroll
            for (int j = 0; j < J_U; ++j) sum += __expf(braw[r0 + j] - mx);
            csm[idx] = __expf(braw[idx] - mx) / sum;
        }
    }
    __syncthreads();
    // ---- stage scaled W panel + x panel ----
    float4* Ws4 = reinterpret_cast<float4*>(Ws);
    for (int i = t; i < 2880; i += 256) {          // 72 rows x 40 float4
        const int row = i / 40, q = i - row * 40;
        const float sc = csm[row * J_U + (q >> 2)];
        const float4 w = Wr4[(size_t)(m0 + row) * 40 + q];
        Ws4[i] = make_float4(w.x * sc, w.y * sc, w.z * sc, w.w * sc);
    }
    for (int i = t; i < 1152; i += 256) {          // 72 rows x 16 float4 (64 b each)
        const int row = i >> 4, col = i & 15;
        const float4 xv = *reinterpret_cast<const float4*>(
            Xt + (size_t)(m0 + row) * B_SZ + bq4 * 64 + col * 4);
        *reinterpret_cast<float4*>(&Xs[row * 64 + col * 4]) = xv;
    }
    __syncthreads();
    // ---- main loop: x b128 + w b64 broadcast; packed fp32 FMA (v_pk_fma_f32) ----
    const int bq = t & 15, ng = t >> 4;
    v2f acc[4][5] = {};                            // pairs along n: (2jj, 2jj+1)
#pragma unroll 4
    for (int m = 0; m < 72; ++m) {
        const float4 cur = *reinterpret_cast<const float4*>(&Xs[m * 64 + bq * 4]);
        const v2f* wr = reinterpret_cast<const v2f*>(Ws + m * N_DIM + ng * J_U);
        v2f xs[4];                                 // 2-lane splats, hoisted per m
        xs[0] = (v2f){cur.x, cur.x};
        xs[1] = (v2f){cur.y, cur.y};
        xs[2] = (v2f){cur.z, cur.z};
        xs[3] = (v2f){cur.w, cur.w};
#pragma unroll
        for (int jj = 0; jj < 5; ++jj) {
            const v2f w2 = wr[jj];
#pragma unroll
            for (int i = 0; i < 4; ++i)
                acc[i][jj] += xs[i] * w2;          // contract -> v_pk_fma_f32
        }
    }
    // ---- store split-K partials as fp16x2 (plain stores, half the bytes) ----
    __half2* sp = s_part + (size_t)ch * 20480 + (size_t)(bq4 * 64 + bq * 4) * 80 + ng * 5;
#pragma unroll
    for (int i = 0; i < 4; ++i)
#pragma unroll
        for (int jj = 0; jj < 5; ++jj)
            sp[(size_t)i * 80 + jj] = __floats2half2_rn(acc[i][jj].x, acc[i][jj].y);
}

// ================= squash: reduce 128 fp16x2 slices (8-way h-split) -> dst ========
// 640 threads = 80 n-pairs x 8 h-groups (16 slices each, fully unrolled).
// fp32 accumulation; +1e-5 added once after the full 128-slice sum (ref order).
__global__ __launch_bounds__(640) void k_squash(const __half2* __restrict__ s_part,
                                                float* __restrict__ dst) {
    __shared__ float2 red[640];                    // [h][80]
    __shared__ float sq[160];
    const int b = blockIdx.x, t = threadIdx.x;
    const int n2 = t % 80, h = t / 80;             // h in 0..7, 16 slices each
    float2 acc = make_float2(0.f, 0.f);
    const __half2* p = s_part + (size_t)h * 16 * 20480 + (size_t)b * 80 + n2;
#pragma unroll
    for (int sl = 0; sl < 16; ++sl) {
        const float2 f = __half22float2(p[(size_t)sl * 20480]);
        acc.x += f.x;
        acc.y += f.y;
    }
    red[t] = acc;
    __syncthreads();
    if (t < 80) {
        float2 s = red[t];
#pragma unroll
        for (int hh = 1; hh < 8; ++hh) {
            const float2 r = red[t + hh * 80];
            s.x += r.x;
            s.y += r.y;
        }
        s.x += 1e-5f;                              // +1e-5 BEFORE magnitudes (ref)
        s.y += 1e-5f;
        sq[2 * t]     = s.x * s.x;
        sq[2 * t + 1] = s.y * s.y;
        red[t] = s;
    }
    __syncthreads();
    if (t < 80) {
        // n = 2t, 2t+1 share j = n>>4 (2t even)
        const int j0 = (t >> 3) * 16;
        float mag = 0.f;
#pragma unroll
        for (int d = 0; d < 16; ++d) mag += sq[j0 + d];
        const float sc = sqrtf(mag) / (1.f + mag);
        const float2 s = red[t];
        dst[(size_t)b * N_DIM + 2 * t]     = s.x * sc;
        dst[(size_t)b * N_DIM + 2 * t + 1] = s.y * sc;
    }
}

// ================= gemm2: 144 m-tiles(64) x 4 b-quarters(64 b) = 576 blocks =========
// R5 structure (XCD swizzle); inner loop on float2 pairs -> v_pk_fma_f32.
__global__ __launch_bounds__(256) void k_gemm2(const float* __restrict__ x,
                                               const float* __restrict__ v,
                                               const float* __restrict__ Wr,
                                               float* __restrict__ agg_part) {
    __shared__ alignas(16) float VG[64 * 164];   // v-panel [64][160] then G-tile [64][164]
    __shared__ float agg[640];                   // 64 c x 10 j
    const int vb = (blockIdx.x % 8) * 72 + (blockIdx.x / 8);    // XCD-aware remap
    const int mt = vb >> 2, bq = vb & 3;
    const int m0 = mt * 64, b0 = bq * 64;
    const int t = threadIdx.x;
    const int tm = t & 15, ng = t >> 4;

    // stage v quarter (packed [64][160])
    float4* Vs4 = reinterpret_cast<float4*>(VG);
    const float4* v4 = reinterpret_cast<const float4*>(v);
    for (int i = t; i < 2560; i += 256) Vs4[i] = v4[(size_t)bq * 2560 + i];
    for (int i = t; i < 640; i += 256) agg[i] = 0.f;
    __syncthreads();

    // main loop over 64 b: x coalesced, v broadcast from LDS; packed fp32 FMA
    v2f acc[4][5] = {};                            // pairs along n
    const float* xb = x + (size_t)b0 * M_DIM + m0 + tm * 4;
    const v2f* Vs2 = reinterpret_cast<const v2f*>(VG);
    float4 pf[4];
#pragma unroll
    for (int i = 0; i < 4; ++i) pf[i] = *reinterpret_cast<const float4*>(xb + (size_t)i * M_DIM);
#pragma unroll 4
    for (int b = 0; b < 64; ++b) {
        const int bf = (b + 4 < 64) ? b + 4 : 63;            // clamped prefetch
        const float4 nxt = *reinterpret_cast<const float4*>(xb + (size_t)bf * M_DIM);
        const float4 cur = pf[0];
        pf[0] = pf[1]; pf[1] = pf[2]; pf[2] = pf[3]; pf[3] = nxt;
        const v2f* vv = Vs2 + b * 80 + ng * 5;
        v2f xs[4];
        xs[0] = (v2f){cur.x, cur.x};
        xs[1] = (v2f){cur.y, cur.y};
        xs[2] = (v2f){cur.z, cur.z};
        xs[3] = (v2f){cur.w, cur.w};
#pragma unroll
        for (int jj = 0; jj < 5; ++jj) {
            const v2f w2 = vv[jj];
#pragma unroll
            for (int i = 0; i < 4; ++i)
                acc[i][jj] += xs[i] * w2;          // contract -> v_pk_fma_f32
        }
    }
    __syncthreads();   // all waves done reading v-panel; reuse VG for G-tile
    // scatter acc -> G-tile (row stride 164 floats; float2 offsets always even)
#pragma unroll
    for (int i = 0; i < 4; ++i)
#pragma unroll
        for (int jj = 0; jj < 5; ++jj)
            *reinterpret_cast<float2*>(&VG[(tm * 4 + i) * 164 + ng * 10 + 2 * jj]) =
                make_float2(acc[i][jj].x, acc[i][jj].y);
    __syncthreads();
    // coalesced fold: 64 rows x 40 float4 of Wr ⊙ G, one j per float4
    const float4* Wr4 = reinterpret_cast<const float4*>(Wr);
    for (int idx = t; idx < 2560; idx += 256) {
        const int row = idx / 40, q = idx - row * 40;
        const float4 w = Wr4[(size_t)(m0 + row) * 40 + q];
        const float4 g = *reinterpret_cast<const float4*>(&VG[row * 164 + q * 4]);
        atomicAdd(&agg[row * J_U + (q >> 2)], w.x * g.x + w.y * g.y + w.z * g.z + w.w * g.w);
    }
    __syncthreads();
    const int k = m0 / C_IN, c0 = m0 - k * C_IN;   // 64-tile never crosses a k-slice
    for (int i = t; i < 640; i += 256)
        agg_part[(size_t)(bq * 8 + k) * 11520 + c0 * J_U + i] = agg[i];
}

extern "C" void kernel_launch(void* const* d_in, const int* in_sizes, int n_in,
                              void* d_out, int out_size, void* d_ws, size_t ws_size,
                              hipStream_t stream) {
    const float* x = (const float*)d_in[0];   // (256, 8, 1152) fp32
    const float* W = (const float*)d_in[1];   // (1, 1152, 10, 16, 8) fp32
    float* out = (float*)d_out;               // (256, 10, 16, 1) fp32
    float* ws  = (float*)d_ws;
    float* Xt   = ws + OFF_XT;
    float* Wr   = ws + OFF_WR;
    __half2* sp = (__half2*)(ws + OFF_SP);
    float* v    = ws + OFF_V;
    float* bij0 = ws + OFF_B0;
    float* bij1 = ws + OFF_B1;
    float* agg  = ws + OFF_AG;
    const float4* Wr4 = (const float4*)Wr;

    k_prep<<<2016, 256, 0, stream>>>(x, W, ws);

    for (int it = 0; it < 4; ++it) {
        const float* bo = (it & 1) ? bij1 : bij0;
        float*       bn = (it & 1) ? bij0 : bij1;
        k_gemm1<<<512, 256, 0, stream>>>(Xt, Wr4, bo, bn, agg, sp, it == 0 ? 1 : 0);
        k_squash<<<256, 640, 0, stream>>>(sp, (it < 3) ? v : out);
        if (it < 3)   // last iteration's agreement is never used
            k_gemm2<<<576, 256, 0, stream>>>(x, v, Wr, agg);
    }
}

// Round 11
// 216.738 us; speedup vs baseline: 1.2399x; 1.1479x over previous
//
#include <hip/hip_runtime.h>
#include <hip/hip_fp16.h>

// Capsule routing via materialized fp16 u_hat (L3-resident), multi-kernel,
// plain stores only. Session ledger: R1 coop grid.sync ~60us -> never.
// R2 contended atomics -> never. R3/R4 occupancy juggling -> regress.
// R5 XCD swizzle 264.7. R8 fp16 split-K 254.7. R9 pk_fma 248.8.
// R10: U[n][c][b] fp16 (94 MB, L3-fit) built once; each iter = 2 streaming
// kernels (gemv-s over c; agreement over b,d with squash folded into its
// prologue -- squash is j-local). 10 launches (was 12), split-K 8 slices.
// R10 bench died to a container infra flake (no pytest verdict); source
// re-audited (bounds/races/hangs: clean) and resubmitted unchanged.
// B=256, K_IN=8, C=1152, J=10, D=16, 4 iters. n = j*16+d.

typedef float v2f __attribute__((ext_vector_type(2)));

#define C_IN  1152
#define J_U   10
#define M_DIM 9216
#define N_DIM 160
#define B_SZ  256

// ---- ws layout (float offsets); ws is 256 MiB = 67.1M floats ----
#define OFF_XT 0              // Xt[9216][256] fp32
#define OFF_U  2400000        // U half[160][1152][256] = 23.6M floats of space
#define OFF_SP 26000000       // s_part fp32 [8][160][256]
#define OFF_B0 26400000       // bij ping [1152][10]
#define OFF_B1 26420000       // bij pong [1152][10]
#define OFF_AG 26440000       // agg [1152][10] (full, written before read)

// ================= prep: transpose x -> Xt (proven 64x64 tile) =================
__global__ __launch_bounds__(256) void k_prep(const float* __restrict__ x,
                                              float* __restrict__ Xt) {
    __shared__ float T[64][65];
    const int bid = blockIdx.x, t = threadIdx.x;
    const int m0 = (bid % 144) * 64, b0 = (bid / 144) * 64;
    {
        const int b_l = t >> 2, q = t & 3;
        const float* xp = x + (size_t)(b0 + b_l) * M_DIM + m0 + q * 16;
#pragma unroll
        for (int u = 0; u < 4; ++u) {
            const float4 v = *reinterpret_cast<const float4*>(xp + 4 * u);
            T[q * 16 + 4 * u + 0][b_l] = v.x;
            T[q * 16 + 4 * u + 1][b_l] = v.y;
            T[q * 16 + 4 * u + 2][b_l] = v.z;
            T[q * 16 + 4 * u + 3][b_l] = v.w;
        }
    }
    __syncthreads();
    {
        const int m_l = t >> 2, q = t & 3;
        float4* op = reinterpret_cast<float4*>(Xt + (size_t)(m0 + m_l) * B_SZ + b0 + q * 16);
#pragma unroll
        for (int u = 0; u < 4; ++u)
            op[u] = make_float4(T[m_l][q * 16 + 4 * u], T[m_l][q * 16 + 4 * u + 1],
                                T[m_l][q * 16 + 4 * u + 2], T[m_l][q * 16 + 4 * u + 3]);
    }
}

// ================= ubuild: U[n][c][b] = sum_k W[c,n,k]*Xt[k*C+c][b] ==============
// 512 blocks = 64 c-chunks(18) x 8 n-chunks(20). Thread = (b-pair, c-half).
// pk_fma on b-pairs; 94 MB fp16 written once (coalesced half2 over b).
__global__ __launch_bounds__(256) void k_ubuild(const float* __restrict__ Xt,
                                                const float* __restrict__ W,
                                                __half2* __restrict__ U2) {
    __shared__ float Wl[2880];                 // [18 c][20 n][8 k]
    const int cc = blockIdx.x >> 3, nc = blockIdx.x & 7;
    const int c0 = cc * 18, n0 = nc * 20;
    const int t = threadIdx.x;
    const float4* W4 = reinterpret_cast<const float4*>(W);
    float4* Wl4 = reinterpret_cast<float4*>(Wl);
    for (int i = t; i < 720; i += 256) {       // 18 c x 20 n x 2 float4
        const int c = i / 40, r = i - c * 40;
        const int n = r >> 1, half = r & 1;
        Wl4[i] = W4[(size_t)(c0 + c) * 320 + (n0 + n) * 2 + half];
    }
    __syncthreads();
    const int b2 = t & 127, ch = t >> 7;
    for (int ci = 0; ci < 9; ++ci) {
        const int c = ch * 9 + ci;             // 0..17
        v2f xk[8];
#pragma unroll
        for (int k = 0; k < 8; ++k)
            xk[k] = *reinterpret_cast<const v2f*>(
                Xt + (size_t)(k * C_IN + c0 + c) * B_SZ + 2 * b2);
#pragma unroll
        for (int n = 0; n < 20; ++n) {
            v2f acc = {0.f, 0.f};
            const float* wp = &Wl[(c * 20 + n) * 8];
#pragma unroll
            for (int k = 0; k < 8; ++k) {
                const float w = wp[k];
                acc += xk[k] * (v2f){w, w};    // v_pk_fma_f32
            }
            U2[((size_t)(n0 + n) * C_IN + c0 + c) * 128 + b2] =
                __floats2half2_rn(acc.x, acc.y);
        }
    }
}

// ================= gemvs: s[n][b] = sum_c csm[c,j(n)] * U[n][c][b] ===============
// 640 blocks = 8 c-eighths(144) x 80 n-pairs. Softmax prologue per block
// (redundant across n-siblings, trivial VALU). Thread = (b-pair, n-half).
__global__ __launch_bounds__(256) void k_gemvs(const __half2* __restrict__ U2,
                                               const float* __restrict__ bij_old,
                                               float* __restrict__ bij_new,
                                               const float* __restrict__ agg,
                                               float* __restrict__ s_part,
                                               int first) {
    __shared__ float braw[1440];
    __shared__ float csm[144];
    const int ce = blockIdx.x / 80, np = blockIdx.x % 80;
    const int c0 = ce * 144, n0 = np * 2, j = np >> 3;   // n-pair never crosses j
    const int t = threadIdx.x;
    if (first) {
        for (int c = t; c < 144; c += 256) csm[c] = 0.1f;   // softmax(0) = 1/J
        if (np == 0)
            for (int i = t; i < 1440; i += 256) bij_new[c0 * J_U + i] = 0.f;
    } else {
        for (int i = t; i < 1440; i += 256) {
            const float v = bij_old[c0 * J_U + i] + agg[c0 * J_U + i];
            braw[i] = v;
            if (np == 0) bij_new[c0 * J_U + i] = v;   // duplicates benign
        }
        __syncthreads();
        for (int c = t; c < 144; c += 256) {
            const int r0 = c * J_U;
            float mx = -1e30f;
#pragma unroll
            for (int q = 0; q < J_U; ++q) mx = fmaxf(mx, braw[r0 + q]);
            float sum = 0.f;
#pragma unroll
            for (int q = 0; q < J_U; ++q) sum += __expf(braw[r0 + q] - mx);
            csm[c] = __expf(braw[r0 + j] - mx) / sum;
        }
    }
    __syncthreads();
    const int b2 = t & 127, nh = t >> 7;
    const int nn = n0 + nh;
    const __half2* up = U2 + ((size_t)nn * C_IN + c0) * 128 + b2;
    v2f acc = {0.f, 0.f};
#pragma unroll 8
    for (int c = 0; c < 144; ++c) {
        const float2 f = __half22float2(up[(size_t)c * 128]);
        const float cs = csm[c];
        acc += (v2f){cs, cs} * (v2f){f.x, f.y};    // v_pk_fma_f32
    }
    *reinterpret_cast<float2*>(s_part + (size_t)ce * 40960 + (size_t)nn * B_SZ + 2 * b2) =
        make_float2(acc.x, acc.y);
}

// ================= agree: agg[c,j] = sum_{b,d} U[j*16+d][c][b] * v[b,d] =========
// 960 blocks = 10 j x 96 c-chunks(12). Prologue: reduce 8 s-slices + squash
// (j-local: mag over d only) -> v in LDS. Main: thread = (b-pair, c-half).
__global__ __launch_bounds__(256) void k_agree(const __half2* __restrict__ U2,
                                               const float* __restrict__ s_part,
                                               float* __restrict__ agg) {
    __shared__ float sv[16 * 256];                 // [d][b]: s then v in place
    __shared__ float red[12 * 128];
    const int j = blockIdx.x / 96, cc = blockIdx.x % 96;
    const int c0 = cc * 12;
    const int t = threadIdx.x;
    for (int i = t; i < 4096; i += 256) {          // reduce slices, +1e-5 (ref order)
        const int d = i >> 8, b = i & 255;
        const float* p = s_part + (size_t)(j * 16 + d) * B_SZ + b;
        float s = 1e-5f;
#pragma unroll
        for (int ce = 0; ce < 8; ++ce) s += p[(size_t)ce * 40960];
        sv[d * 256 + b] = s;
    }
    __syncthreads();
    {                                              // squash per b (t = b)
        float mag = 0.f;
#pragma unroll
        for (int d = 0; d < 16; ++d) { const float xx = sv[d * 256 + t]; mag += xx * xx; }
        const float sc = sqrtf(mag) / (1.f + mag);
#pragma unroll
        for (int d = 0; d < 16; ++d) sv[d * 256 + t] *= sc;
    }
    __syncthreads();
    const int b2 = t & 127, ch = t >> 7;
    float acc[6] = {};
#pragma unroll
    for (int ci = 0; ci < 6; ++ci) {
        const int c = c0 + ch * 6 + ci;
        const __half2* up = U2 + ((size_t)(j * 16) * C_IN + c) * 128 + b2;
#pragma unroll
        for (int d = 0; d < 16; ++d) {
            const float2 f = __half22float2(up[(size_t)d * C_IN * 128]);
            const float2 vv = *reinterpret_cast<const float2*>(&sv[d * 256 + 2 * b2]);
            acc[ci] += f.x * vv.x + f.y * vv.y;
        }
    }
#pragma unroll
    for (int ci = 0; ci < 6; ++ci) red[(ch * 6 + ci) * 128 + b2] = acc[ci];
    __syncthreads();
#pragma unroll
    for (int pass = 0; pass < 3; ++pass) {         // 12 rows x reduce-128
        const int r = pass * 4 + (t >> 6), l = t & 63;
        float v = red[r * 128 + l] + red[r * 128 + l + 64];
#pragma unroll
        for (int off = 32; off > 0; off >>= 1) v += __shfl_down(v, off);
        if (l == 0) agg[(size_t)(c0 + r) * J_U + j] = v;
    }
}

// ================= sqout: final squash s_part -> out =================
__global__ __launch_bounds__(256) void k_sqout(const float* __restrict__ s_part,
                                               float* __restrict__ out) {
    __shared__ float sl[16 * 32];
    const int j = blockIdx.x >> 3, bc = blockIdx.x & 7;
    const int b0 = bc * 32;
    const int t = threadIdx.x;
    for (int i = t; i < 512; i += 256) {
        const int d = i >> 5, bl = i & 31;
        const float* p = s_part + (size_t)(j * 16 + d) * B_SZ + b0 + bl;
        float s = 1e-5f;
#pragma unroll
        for (int ce = 0; ce < 8; ++ce) s += p[(size_t)ce * 40960];
        sl[d * 32 + bl] = s;
    }
    __syncthreads();
    if (t < 32) {
        float mag = 0.f;
#pragma unroll
        for (int d = 0; d < 16; ++d) { const float xx = sl[d * 32 + t]; mag += xx * xx; }
        const float sc = sqrtf(mag) / (1.f + mag);
#pragma unroll
        for (int d = 0; d < 16; ++d)
            out[(size_t)(b0 + t) * N_DIM + j * 16 + d] = sl[d * 32 + t] * sc;
    }
}

extern "C" void kernel_launch(void* const* d_in, const int* in_sizes, int n_in,
                              void* d_out, int out_size, void* d_ws, size_t ws_size,
                              hipStream_t stream) {
    const float* x = (const float*)d_in[0];   // (256, 8, 1152) fp32
    const float* W = (const float*)d_in[1];   // (1, 1152, 10, 16, 8) fp32
    float* out = (float*)d_out;               // (256, 10, 16, 1) fp32
    float* ws  = (float*)d_ws;
    float* Xt   = ws + OFF_XT;
    __half2* U2 = (__half2*)(ws + OFF_U);
    float* sp   = ws + OFF_SP;
    float* bij0 = ws + OFF_B0;
    float* bij1 = ws + OFF_B1;
    float* agg  = ws + OFF_AG;

    k_prep<<<576, 256, 0, stream>>>(x, Xt);
    k_ubuild<<<512, 256, 0, stream>>>(Xt, W, U2);

    for (int it = 0; it < 4; ++it) {
        const float* bo = (it & 1) ? bij1 : bij0;
        float*       bn = (it & 1) ? bij0 : bij1;
        k_gemvs<<<640, 256, 0, stream>>>(U2, bo, bn, agg, sp, it == 0 ? 1 : 0);
        if (it < 3)
            k_agree<<<960, 256, 0, stream>>>(U2, sp, agg);
    }
    k_sqout<<<80, 256, 0, stream>>>(sp, out);
}